// Round 1
// baseline (14902.098 us; speedup 1.0000x reference)
//
#include <hip/hip_runtime.h>
#include <cstddef>

// Problem constants (fixed by reference): B=64, T=128, C=4096, H=32, HS=128
#define NB 64
#define NH 32
#define NT 128
#define NHS 128
#define NC 4096
#define SCALE 0.17677669529663687f  // 32^-0.5

// ---------------------------------------------------------------------------
// Kernel 1: QKV projection. Per (b,h): O[t,s] = sum_c x[b,t,c] * w[h,c,s]
// grid.x = B*H (2048), grid.y = 3 (q/k/v). 256 threads, 128x128 tile, 8x8/thread.
// ---------------------------------------------------------------------------
__global__ __launch_bounds__(256) void qkv_kernel(
    const float* __restrict__ x,
    const float* __restrict__ wq, const float* __restrict__ wk, const float* __restrict__ wv,
    float* __restrict__ q, float* __restrict__ k, float* __restrict__ v)
{
    const int bh = blockIdx.x;
    const int b  = bh >> 5;   // /H
    const int h  = bh & 31;   // %H
    const float* w; float* o;
    if (blockIdx.y == 0)      { w = wq; o = q; }
    else if (blockIdx.y == 1) { w = wk; o = k; }
    else                      { w = wv; o = v; }
    const float* A  = x + (size_t)b * NT * NC;      // [T][C] row-major
    const float* Bm = w + (size_t)h * NC * NHS;     // [C][HS] row-major
    float* O = o + (size_t)bh * NT * NHS;           // [T][HS]

    __shared__ float As[16][128];   // [kk][t]
    __shared__ float Bs[16][128];   // [kk][s]

    const int tid = threadIdx.x;
    const int tx = tid & 15;        // s-tile coord
    const int ty = tid >> 4;        // t-tile coord
    float acc[8][8] = {};

    for (int c0 = 0; c0 < NC; c0 += 16) {
        #pragma unroll
        for (int it = 0; it < 8; ++it) {
            int idx = it * 256 + tid;
            As[idx & 15][idx >> 4] = A[(size_t)(idx >> 4) * NC + c0 + (idx & 15)];
        }
        #pragma unroll
        for (int it = 0; it < 8; ++it) {
            int idx = it * 256 + tid;
            Bs[idx >> 7][idx & 127] = Bm[(size_t)(c0 + (idx >> 7)) * NHS + (idx & 127)];
        }
        __syncthreads();
        #pragma unroll
        for (int kk = 0; kk < 16; ++kk) {
            float4 a0 = *(const float4*)&As[kk][ty * 8];
            float4 a1 = *(const float4*)&As[kk][ty * 8 + 4];
            float4 b0 = *(const float4*)&Bs[kk][tx * 8];
            float4 b1 = *(const float4*)&Bs[kk][tx * 8 + 4];
            float a[8]  = {a0.x, a0.y, a0.z, a0.w, a1.x, a1.y, a1.z, a1.w};
            float bb[8] = {b0.x, b0.y, b0.z, b0.w, b1.x, b1.y, b1.z, b1.w};
            #pragma unroll
            for (int i = 0; i < 8; ++i)
                #pragma unroll
                for (int j = 0; j < 8; ++j)
                    acc[i][j] = fmaf(a[i], bb[j], acc[i][j]);
        }
        __syncthreads();
    }
    #pragma unroll
    for (int i = 0; i < 8; ++i) {
        const int t = ty * 8 + i;
        #pragma unroll
        for (int j = 0; j < 8; j += 4) {
            float4 vv = make_float4(acc[i][j], acc[i][j+1], acc[i][j+2], acc[i][j+3]);
            *(float4*)&O[(size_t)t * NHS + tx * 8 + j] = vv;
        }
    }
}

// ---------------------------------------------------------------------------
// Kernel 2: fused attention per (b,h). S = scale*Q*K^T; softmax over t (query
// axis, per reference!) for each column u; O = S~ * V. S in 64KB LDS.
// grid.x = B*H (2048), 256 threads.
// ---------------------------------------------------------------------------
__global__ __launch_bounds__(256) void attn_kernel(
    const float* __restrict__ q, const float* __restrict__ k,
    const float* __restrict__ v, float* __restrict__ o)
{
    const int bh = blockIdx.x;
    const float* Q = q + (size_t)bh * NT * NHS;
    const float* K = k + (size_t)bh * NT * NHS;
    const float* V = v + (size_t)bh * NT * NHS;
    float* O = o + (size_t)bh * NT * NHS;

    __shared__ float S[NT * NT];   // S[t*128 + u], exactly 64 KB

    const int tid = threadIdx.x;
    const int tx = tid & 15;   // u-coord (phase1) / s-coord (phase3)
    const int ty = tid >> 4;   // t-coord
    float acc[8][8] = {};

    // Phase 1: S = scale * Q K^T  (contraction over s)
    for (int s0 = 0; s0 < NHS; s0 += 4) {
        float4 a4[8], b4[8];
        #pragma unroll
        for (int i = 0; i < 8; ++i) a4[i] = *(const float4*)&Q[(size_t)(ty * 8 + i) * NHS + s0];
        #pragma unroll
        for (int j = 0; j < 8; ++j) b4[j] = *(const float4*)&K[(size_t)(tx * 8 + j) * NHS + s0];
        #pragma unroll
        for (int i = 0; i < 8; ++i)
            #pragma unroll
            for (int j = 0; j < 8; ++j)
                acc[i][j] += a4[i].x * b4[j].x + a4[i].y * b4[j].y
                           + a4[i].z * b4[j].z + a4[i].w * b4[j].w;
    }
    #pragma unroll
    for (int i = 0; i < 8; ++i)
        #pragma unroll
        for (int j = 0; j < 8; ++j)
            S[(ty * 8 + i) * NT + (tx * 8 + j)] = acc[i][j] * SCALE;
    __syncthreads();

    // Phase 2: softmax over t for each column u (one thread per column)
    if (tid < NT) {
        const int u = tid;
        float m = -1e30f;
        for (int t = 0; t < NT; ++t) m = fmaxf(m, S[t * NT + u]);
        float sum = 0.f;
        for (int t = 0; t < NT; ++t) {
            float e = __expf(S[t * NT + u] - m);
            S[t * NT + u] = e;
            sum += e;
        }
        const float inv = 1.0f / sum;
        for (int t = 0; t < NT; ++t) S[t * NT + u] *= inv;
    }
    __syncthreads();

    // Phase 3: O = S~ @ V (contraction over u); V streamed from global (L1/L2 hits)
    #pragma unroll
    for (int i = 0; i < 8; ++i)
        #pragma unroll
        for (int j = 0; j < 8; ++j)
            acc[i][j] = 0.f;
    for (int u = 0; u < NT; ++u) {
        float4 va = *(const float4*)&V[(size_t)u * NHS + tx * 8];
        float4 vb = *(const float4*)&V[(size_t)u * NHS + tx * 8 + 4];
        #pragma unroll
        for (int i = 0; i < 8; ++i) {
            float sv = S[(ty * 8 + i) * NT + u];
            acc[i][0] = fmaf(sv, va.x, acc[i][0]);
            acc[i][1] = fmaf(sv, va.y, acc[i][1]);
            acc[i][2] = fmaf(sv, va.z, acc[i][2]);
            acc[i][3] = fmaf(sv, va.w, acc[i][3]);
            acc[i][4] = fmaf(sv, vb.x, acc[i][4]);
            acc[i][5] = fmaf(sv, vb.y, acc[i][5]);
            acc[i][6] = fmaf(sv, vb.z, acc[i][6]);
            acc[i][7] = fmaf(sv, vb.w, acc[i][7]);
        }
    }
    #pragma unroll
    for (int i = 0; i < 8; ++i) {
        const int t = ty * 8 + i;
        #pragma unroll
        for (int j = 0; j < 8; j += 4) {
            float4 vv = make_float4(acc[i][j], acc[i][j+1], acc[i][j+2], acc[i][j+3]);
            *(float4*)&O[(size_t)t * NHS + tx * 8 + j] = vv;
        }
    }
}

// ---------------------------------------------------------------------------
// Kernel 3: final projection. out[b,s,o] = sum_e attn[b,e,s] * wp[o,e] + bp[o]
// where attn is [B, H*T=4096, HS=128] (e-major, s contiguous).
// grid.x = B * (C/128) = 2048. 256 threads, 128(s) x 128(o) tile.
// ---------------------------------------------------------------------------
__global__ __launch_bounds__(256) void proj_kernel(
    const float* __restrict__ attn, const float* __restrict__ wp,
    const float* __restrict__ bp, float* __restrict__ out)
{
    const int b  = blockIdx.x >> 5;       // /32
    const int o0 = (blockIdx.x & 31) * 128;
    const float* A = attn + (size_t)b * NC * NHS;   // A[e*128 + s]

    __shared__ float As[16][128];   // [kk][s]
    __shared__ float Bs[16][128];   // [kk][o]

    const int tid = threadIdx.x;
    const int tx = tid & 15;   // o-coord
    const int ty = tid >> 4;   // s-coord
    float acc[8][8] = {};

    for (int e0 = 0; e0 < NC; e0 += 16) {
        #pragma unroll
        for (int it = 0; it < 8; ++it) {
            int idx = it * 256 + tid;   // s = idx&127, kk = idx>>7
            As[idx >> 7][idx & 127] = A[(size_t)(e0 + (idx >> 7)) * NHS + (idx & 127)];
        }
        #pragma unroll
        for (int it = 0; it < 8; ++it) {
            int idx = it * 256 + tid;   // kk = idx&15, o = idx>>4
            Bs[idx & 15][idx >> 4] = wp[(size_t)(o0 + (idx >> 4)) * NC + e0 + (idx & 15)];
        }
        __syncthreads();
        #pragma unroll
        for (int kk = 0; kk < 16; ++kk) {
            float4 a0 = *(const float4*)&As[kk][ty * 8];
            float4 a1 = *(const float4*)&As[kk][ty * 8 + 4];
            float4 b0 = *(const float4*)&Bs[kk][tx * 8];
            float4 b1 = *(const float4*)&Bs[kk][tx * 8 + 4];
            float a[8]  = {a0.x, a0.y, a0.z, a0.w, a1.x, a1.y, a1.z, a1.w};
            float bb[8] = {b0.x, b0.y, b0.z, b0.w, b1.x, b1.y, b1.z, b1.w};
            #pragma unroll
            for (int i = 0; i < 8; ++i)
                #pragma unroll
                for (int j = 0; j < 8; ++j)
                    acc[i][j] = fmaf(a[i], bb[j], acc[i][j]);
        }
        __syncthreads();
    }
    #pragma unroll
    for (int i = 0; i < 8; ++i) {
        const int s = ty * 8 + i;
        #pragma unroll
        for (int j = 0; j < 8; j += 4) {
            int oc = o0 + tx * 8 + j;
            float4 vv = make_float4(acc[i][j]   + bp[oc],
                                    acc[i][j+1] + bp[oc+1],
                                    acc[i][j+2] + bp[oc+2],
                                    acc[i][j+3] + bp[oc+3]);
            *(float4*)&out[((size_t)b * NHS + s) * NC + oc] = vv;
        }
    }
}

// ---------------------------------------------------------------------------
extern "C" void kernel_launch(void* const* d_in, const int* in_sizes, int n_in,
                              void* d_out, int out_size, void* d_ws, size_t ws_size,
                              hipStream_t stream) {
    const float* x  = (const float*)d_in[0];
    const float* wq = (const float*)d_in[1];
    const float* wk = (const float*)d_in[2];
    const float* wv = (const float*)d_in[3];
    const float* wp = (const float*)d_in[4];
    const float* bp = (const float*)d_in[5];
    float* out = (float*)d_out;

    // Workspace layout: q, k, v, attn — each B*H*T*HS = 33,554,432 floats (134 MB)
    const size_t NE = (size_t)NB * NH * NT * NHS;
    float* ws   = (float*)d_ws;
    float* q    = ws;
    float* k    = ws + NE;
    float* v    = ws + 2 * NE;
    float* attn = ws + 3 * NE;

    dim3 g1(NB * NH, 3);
    qkv_kernel<<<g1, 256, 0, stream>>>(x, wq, wk, wv, q, k, v);
    attn_kernel<<<NB * NH, 256, 0, stream>>>(q, k, v, attn);
    proj_kernel<<<NB * NH, 256, 0, stream>>>(attn, wp, bp, out);
}

// Round 2
// 2080.611 us; speedup vs baseline: 7.1624x; 7.1624x over previous
//
#include <hip/hip_runtime.h>
#include <cstddef>
#include <cstdint>

// Problem constants (fixed by reference): B=64, T=128, C=4096, H=32, HS=128
#define NB 64
#define NH 32
#define NT 128
#define NHS 128
#define NC 4096
#define SCALE 0.17677669529663687f  // 32^-0.5

typedef __bf16 bf16_t;
typedef __bf16 bf16x8 __attribute__((ext_vector_type(8)));
typedef __bf16 bf16x4 __attribute__((ext_vector_type(4)));
typedef float  f32x4  __attribute__((ext_vector_type(4)));

// Async global->LDS, 16B per lane. LDS dest must be wave-uniform base + lane*16.
__device__ __forceinline__ void load_lds16(const bf16_t* g, bf16_t* l) {
    __builtin_amdgcn_global_load_lds(
        (const __attribute__((address_space(1))) char*)g,
        (__attribute__((address_space(3))) char*)l,
        16, 0, 0);
}

// ---------------------------------------------------------------------------
// Conversion: fp32 -> bf16, 8 elements/thread (n must be divisible by 8)
// ---------------------------------------------------------------------------
__global__ __launch_bounds__(256) void cvt_bf16_kernel(
    const float* __restrict__ in, bf16_t* __restrict__ out, int n8)
{
    int i = blockIdx.x * 256 + threadIdx.x;
    if (i >= n8) return;
    const float4* p = (const float4*)in + (size_t)i * 2;
    float4 a = p[0], b = p[1];
    bf16x8 o;
    o[0] = (bf16_t)a.x; o[1] = (bf16_t)a.y; o[2] = (bf16_t)a.z; o[3] = (bf16_t)a.w;
    o[4] = (bf16_t)b.x; o[5] = (bf16_t)b.y; o[6] = (bf16_t)b.z; o[7] = (bf16_t)b.w;
    ((bf16x8*)out)[i] = o;
}

// ---------------------------------------------------------------------------
// Conversion + transpose: w [H][C][HS] fp32 -> wT [H][HS][C] bf16.
// 64x64 tile per block, 256 threads. grid.x = H*(C/64)*(HS/64) = 4096, grid.y = 3.
// ---------------------------------------------------------------------------
__global__ __launch_bounds__(256) void cvt_w_transpose_kernel(
    const float* __restrict__ wq, const float* __restrict__ wk, const float* __restrict__ wv,
    bf16_t* __restrict__ qt, bf16_t* __restrict__ kt, bf16_t* __restrict__ vt)
{
    const float* w; bf16_t* o;
    if (blockIdx.y == 0)      { w = wq; o = qt; }
    else if (blockIdx.y == 1) { w = wk; o = kt; }
    else                      { w = wv; o = vt; }
    const int h   = blockIdx.x >> 7;         // 32 heads
    const int rem = blockIdx.x & 127;        // 64 c-tiles x 2 s-tiles
    const int c0  = (rem >> 1) * 64;
    const int s0  = (rem & 1) * 64;
    const float* W = w + (size_t)h * NC * NHS;
    bf16_t* O = o + (size_t)h * NHS * NC;

    __shared__ float t[64][65];
    const int tid = threadIdx.x;
    #pragma unroll
    for (int it = 0; it < 16; ++it) {
        int idx = it * 256 + tid;
        int r = idx >> 6, cc = idx & 63;           // r: c-offset, cc: s-offset
        t[r][cc] = W[(size_t)(c0 + r) * NHS + s0 + cc];
    }
    __syncthreads();
    #pragma unroll
    for (int it = 0; it < 16; ++it) {
        int idx = it * 256 + tid;
        int sr = idx >> 6, cr = idx & 63;          // sr: s-offset, cr: c-offset
        O[(size_t)(s0 + sr) * NC + c0 + cr] = (bf16_t)t[cr][sr];
    }
}

// ---------------------------------------------------------------------------
// Core MFMA GEMM: D(128x128) = A(128xK) * BT(128xK)^T, K=4096, bf16 inputs.
// Both A and BT are row-major with K contiguous. m97-style staging.
// 256 threads = 4 waves; wave computes 64x64 via 4x4 grid of 16x16x32 MFMA.
// ---------------------------------------------------------------------------
__device__ __forceinline__ void gemm128x128(
    const bf16_t* __restrict__ A, const bf16_t* __restrict__ BT,
    int ldA, int ldBT, f32x4 acc[4][4])
{
    __shared__ bf16_t As[128 * 32];
    __shared__ bf16_t Bs[128 * 32];

    const int tid  = threadIdx.x;
    const int lane = tid & 63;
    const int wave = tid >> 6;
    const int wr = (wave >> 1) * 64;
    const int wc = (wave & 1) * 64;

    // staging map: thread tid covers row (tid>>2), 8-elem chunk (tid&3) -> LDS byte addr 16*tid
    const int srow = tid >> 2;
    const int scol = (tid & 3) * 8;

    const int m0 = wr + (lane & 15);
    const int n0 = wc + (lane & 15);
    const int kq = (lane >> 4) * 8;

    for (int k0 = 0; k0 < NC; k0 += 32) {
        load_lds16(A  + (size_t)srow        * ldA  + k0 + scol, &As[srow * 32 + scol]);
        load_lds16(A  + (size_t)(srow + 64) * ldA  + k0 + scol, &As[(srow + 64) * 32 + scol]);
        load_lds16(BT + (size_t)srow        * ldBT + k0 + scol, &Bs[srow * 32 + scol]);
        load_lds16(BT + (size_t)(srow + 64) * ldBT + k0 + scol, &Bs[(srow + 64) * 32 + scol]);
        __syncthreads();

        bf16x8 af[4], bfr[4];
        #pragma unroll
        for (int i = 0; i < 4; ++i) af[i]  = *(const bf16x8*)&As[(m0 + i * 16) * 32 + kq];
        #pragma unroll
        for (int j = 0; j < 4; ++j) bfr[j] = *(const bf16x8*)&Bs[(n0 + j * 16) * 32 + kq];
        #pragma unroll
        for (int i = 0; i < 4; ++i)
            #pragma unroll
            for (int j = 0; j < 4; ++j)
                acc[i][j] = __builtin_amdgcn_mfma_f32_16x16x32_bf16(af[i], bfr[j], acc[i][j], 0, 0, 0);
        __syncthreads();
    }
}

// ---------------------------------------------------------------------------
// QKV GEMM: per (b,h): q/k/v[bh][t][s] = x_bf[b] (128x4096) * wT[h] (128x4096)^T
// grid.x = B*H = 2048, grid.y = 3. Output bf16, ld=128.
// ---------------------------------------------------------------------------
__global__ __launch_bounds__(256) void qkv_mfma_kernel(
    const bf16_t* __restrict__ x,
    const bf16_t* __restrict__ wqT, const bf16_t* __restrict__ wkT, const bf16_t* __restrict__ wvT,
    bf16_t* __restrict__ q, bf16_t* __restrict__ k, bf16_t* __restrict__ v)
{
    const int bh = blockIdx.x;
    const int b = bh >> 5, h = bh & 31;
    const bf16_t* wT; bf16_t* o;
    if (blockIdx.y == 0)      { wT = wqT; o = q; }
    else if (blockIdx.y == 1) { wT = wkT; o = k; }
    else                      { wT = wvT; o = v; }

    const bf16_t* A  = x  + (size_t)b * NT * NC;
    const bf16_t* BT = wT + (size_t)h * NHS * NC;
    bf16_t* D = o + (size_t)bh * NT * NHS;

    f32x4 acc[4][4] = {};
    gemm128x128(A, BT, NC, NC, acc);

    const int lane = threadIdx.x & 63;
    const int wave = threadIdx.x >> 6;
    const int wr = (wave >> 1) * 64;
    const int wc = (wave & 1) * 64;
    const int rbase = wr + (lane >> 4) * 4;
    const int col  = wc + (lane & 15);
    #pragma unroll
    for (int i = 0; i < 4; ++i)
        #pragma unroll
        for (int j = 0; j < 4; ++j)
            #pragma unroll
            for (int r = 0; r < 4; ++r)
                D[(size_t)(rbase + i * 16 + r) * NHS + col + j * 16] = (bf16_t)acc[i][j][r];
}

// ---------------------------------------------------------------------------
// Attention per (b,h), bf16 in, column-softmax (query axis), writes TRANSPOSED
// bf16 output attnT[b][s][h*T + t] so proj GEMM's A is K-contiguous.
// grid.x = B*H = 2048, 256 threads. S (128x128 fp32) in 64KB LDS.
// ---------------------------------------------------------------------------
__global__ __launch_bounds__(256) void attn_kernel(
    const bf16_t* __restrict__ q, const bf16_t* __restrict__ k,
    const bf16_t* __restrict__ v, bf16_t* __restrict__ attnT)
{
    const int bh = blockIdx.x;
    const int b = bh >> 5, h = bh & 31;
    const bf16_t* Q = q + (size_t)bh * NT * NHS;
    const bf16_t* K = k + (size_t)bh * NT * NHS;
    const bf16_t* V = v + (size_t)bh * NT * NHS;
    bf16_t* AT = attnT + (size_t)b * NHS * NC;

    __shared__ float S[NT * NT];   // 64 KB

    const int tid = threadIdx.x;
    const int tx = tid & 15;
    const int ty = tid >> 4;
    float acc[8][8] = {};

    // Phase 1: S = scale * Q K^T
    for (int s0 = 0; s0 < NHS; s0 += 4) {
        float qf[8][4], kf[8][4];
        #pragma unroll
        for (int i = 0; i < 8; ++i) {
            bf16x4 t = *(const bf16x4*)&Q[(size_t)(ty * 8 + i) * NHS + s0];
            qf[i][0] = (float)t[0]; qf[i][1] = (float)t[1]; qf[i][2] = (float)t[2]; qf[i][3] = (float)t[3];
        }
        #pragma unroll
        for (int j = 0; j < 8; ++j) {
            bf16x4 t = *(const bf16x4*)&K[(size_t)(tx * 8 + j) * NHS + s0];
            kf[j][0] = (float)t[0]; kf[j][1] = (float)t[1]; kf[j][2] = (float)t[2]; kf[j][3] = (float)t[3];
        }
        #pragma unroll
        for (int i = 0; i < 8; ++i)
            #pragma unroll
            for (int j = 0; j < 8; ++j) {
                acc[i][j] = fmaf(qf[i][0], kf[j][0], acc[i][j]);
                acc[i][j] = fmaf(qf[i][1], kf[j][1], acc[i][j]);
                acc[i][j] = fmaf(qf[i][2], kf[j][2], acc[i][j]);
                acc[i][j] = fmaf(qf[i][3], kf[j][3], acc[i][j]);
            }
    }
    #pragma unroll
    for (int i = 0; i < 8; ++i)
        #pragma unroll
        for (int j = 0; j < 8; ++j)
            S[(ty * 8 + i) * NT + (tx * 8 + j)] = acc[i][j] * SCALE;
    __syncthreads();

    // Phase 2: softmax over t (query axis) per column u — one thread per column
    if (tid < NT) {
        const int u = tid;
        float m = -1e30f;
        for (int t = 0; t < NT; ++t) m = fmaxf(m, S[t * NT + u]);
        float sum = 0.f;
        for (int t = 0; t < NT; ++t) {
            float e = __expf(S[t * NT + u] - m);
            S[t * NT + u] = e;
            sum += e;
        }
        const float inv = 1.0f / sum;
        for (int t = 0; t < NT; ++t) S[t * NT + u] *= inv;
    }
    __syncthreads();

    // Phase 3: O = S~ @ V
    #pragma unroll
    for (int i = 0; i < 8; ++i)
        #pragma unroll
        for (int j = 0; j < 8; ++j)
            acc[i][j] = 0.f;
    for (int u = 0; u < NT; ++u) {
        bf16x8 vv = *(const bf16x8*)&V[(size_t)u * NHS + tx * 8];
        float vf[8];
        #pragma unroll
        for (int e = 0; e < 8; ++e) vf[e] = (float)vv[e];
        #pragma unroll
        for (int i = 0; i < 8; ++i) {
            float sv = S[(ty * 8 + i) * NT + u];
            #pragma unroll
            for (int e = 0; e < 8; ++e)
                acc[i][e] = fmaf(sv, vf[e], acc[i][e]);
        }
    }
    // Transposed write: AT[s][h*T + t], 8 consecutive t per 16B store
    #pragma unroll
    for (int j = 0; j < 8; ++j) {
        bf16x8 pack;
        #pragma unroll
        for (int i = 0; i < 8; ++i) pack[i] = (bf16_t)acc[i][j];
        *(bf16x8*)&AT[(size_t)(tx * 8 + j) * NC + h * NT + ty * 8] = pack;
    }
}

// ---------------------------------------------------------------------------
// Final projection: out[b][s][o] = attnT[b] (128x4096) * wp_bf (o-row, 4096)^T + bp
// grid.x = B = 64, grid.y = C/128 = 32. Output fp32.
// ---------------------------------------------------------------------------
__global__ __launch_bounds__(256) void proj_mfma_kernel(
    const bf16_t* __restrict__ attnT, const bf16_t* __restrict__ wpb,
    const float* __restrict__ bp, float* __restrict__ out)
{
    const int b  = blockIdx.x;
    const int o0 = blockIdx.y * 128;
    const bf16_t* A  = attnT + (size_t)b * NHS * NC;
    const bf16_t* BT = wpb + (size_t)o0 * NC;

    f32x4 acc[4][4] = {};
    gemm128x128(A, BT, NC, NC, acc);

    float* D = out + (size_t)b * NHS * NC + o0;
    const int lane = threadIdx.x & 63;
    const int wave = threadIdx.x >> 6;
    const int wr = (wave >> 1) * 64;
    const int wc = (wave & 1) * 64;
    const int rbase = wr + (lane >> 4) * 4;
    #pragma unroll
    for (int i = 0; i < 4; ++i)
        #pragma unroll
        for (int j = 0; j < 4; ++j) {
            const int n = wc + j * 16 + (lane & 15);
            const float bias = bp[o0 + n];
            #pragma unroll
            for (int r = 0; r < 4; ++r)
                D[(size_t)(rbase + i * 16 + r) * NC + n] = acc[i][j][r] + bias;
        }
}

// ---------------------------------------------------------------------------
extern "C" void kernel_launch(void* const* d_in, const int* in_sizes, int n_in,
                              void* d_out, int out_size, void* d_ws, size_t ws_size,
                              hipStream_t stream) {
    const float* x  = (const float*)d_in[0];
    const float* wq = (const float*)d_in[1];
    const float* wk = (const float*)d_in[2];
    const float* wv = (const float*)d_in[3];
    const float* wp = (const float*)d_in[4];
    const float* bp = (const float*)d_in[5];
    float* out = (float*)d_out;

    // Workspace layout (bf16 elements); total 469.8 MB
    const size_t NX = (size_t)NB * NT * NC;     // 33,554,432
    const size_t NW = (size_t)NH * NC * NHS;    // 16,777,216
    bf16_t* xb  = (bf16_t*)d_ws;
    bf16_t* wqT = xb  + NX;
    bf16_t* wkT = wqT + NW;
    bf16_t* wvT = wkT + NW;
    bf16_t* wpb = wvT + NW;
    bf16_t* qb  = wpb + NW;
    bf16_t* kb  = qb  + NX;
    bf16_t* vb  = kb  + NX;
    bf16_t* atT = vb  + NX;

    // 1. Conversions
    cvt_bf16_kernel<<<(int)(NX / 8 / 256), 256, 0, stream>>>(x, xb, (int)(NX / 8));
    cvt_w_transpose_kernel<<<dim3(4096, 3), 256, 0, stream>>>(wq, wk, wv, wqT, wkT, wvT);
    cvt_bf16_kernel<<<(int)(NW / 8 / 256), 256, 0, stream>>>(wp, wpb, (int)(NW / 8));

    // 2. QKV projections (MFMA)
    qkv_mfma_kernel<<<dim3(NB * NH, 3), 256, 0, stream>>>(xb, wqT, wkT, wvT, qb, kb, vb);

    // 3. Attention (writes transposed bf16)
    attn_kernel<<<NB * NH, 256, 0, stream>>>(qb, kb, vb, atT);

    // 4. Output projection (MFMA, fp32 out + bias)
    proj_mfma_kernel<<<dim3(NB, 32), 256, 0, stream>>>(atT, wpb, bp, out);
}

// Round 3
// 1685.205 us; speedup vs baseline: 8.8429x; 1.2346x over previous
//
#include <hip/hip_runtime.h>
#include <cstddef>
#include <cstdint>

// Problem constants (fixed by reference): B=64, T=128, C=4096, H=32, HS=128
#define NB 64
#define NH 32
#define NT 128
#define NHS 128
#define NC 4096
#define SCALE 0.17677669529663687f  // 32^-0.5
#define SLD 136                      // bf16 leading dim for attention score tile

typedef __bf16 bf16_t;
typedef __bf16 bf16x8 __attribute__((ext_vector_type(8)));
typedef float  f32x4  __attribute__((ext_vector_type(4)));

// Async global->LDS, 16B per lane. LDS dest must be wave-uniform base + lane*16.
__device__ __forceinline__ void load_lds16(const bf16_t* g, bf16_t* l) {
    __builtin_amdgcn_global_load_lds(
        (const __attribute__((address_space(1))) char*)g,
        (__attribute__((address_space(3))) char*)l,
        16, 0, 0);
}

// ---------------------------------------------------------------------------
// Conversion: fp32 -> bf16, 8 elements/thread
// ---------------------------------------------------------------------------
__global__ __launch_bounds__(256) void cvt_bf16_kernel(
    const float* __restrict__ in, bf16_t* __restrict__ out, int n8)
{
    int i = blockIdx.x * 256 + threadIdx.x;
    if (i >= n8) return;
    const float4* p = (const float4*)in + (size_t)i * 2;
    float4 a = p[0], b = p[1];
    bf16x8 o;
    o[0] = (bf16_t)a.x; o[1] = (bf16_t)a.y; o[2] = (bf16_t)a.z; o[3] = (bf16_t)a.w;
    o[4] = (bf16_t)b.x; o[5] = (bf16_t)b.y; o[6] = (bf16_t)b.z; o[7] = (bf16_t)b.w;
    ((bf16x8*)out)[i] = o;
}

// ---------------------------------------------------------------------------
// Conversion + transpose: w [H][C][HS] fp32 -> wT [H][HS][C] bf16.
// ---------------------------------------------------------------------------
__global__ __launch_bounds__(256) void cvt_w_transpose_kernel(
    const float* __restrict__ wq, const float* __restrict__ wk, const float* __restrict__ wv,
    bf16_t* __restrict__ qt, bf16_t* __restrict__ kt, bf16_t* __restrict__ vt)
{
    const float* w; bf16_t* o;
    if (blockIdx.y == 0)      { w = wq; o = qt; }
    else if (blockIdx.y == 1) { w = wk; o = kt; }
    else                      { w = wv; o = vt; }
    const int h   = blockIdx.x >> 7;
    const int rem = blockIdx.x & 127;
    const int c0  = (rem >> 1) * 64;
    const int s0  = (rem & 1) * 64;
    const float* W = w + (size_t)h * NC * NHS;
    bf16_t* O = o + (size_t)h * NHS * NC;

    __shared__ float t[64][65];
    const int tid = threadIdx.x;
    #pragma unroll
    for (int it = 0; it < 16; ++it) {
        int idx = it * 256 + tid;
        int r = idx >> 6, cc = idx & 63;
        t[r][cc] = W[(size_t)(c0 + r) * NHS + s0 + cc];
    }
    __syncthreads();
    #pragma unroll
    for (int it = 0; it < 16; ++it) {
        int idx = it * 256 + tid;
        int sr = idx >> 6, cr = idx & 63;
        O[(size_t)(s0 + sr) * NC + c0 + cr] = (bf16_t)t[cr][sr];
    }
}

// ---------------------------------------------------------------------------
// Core MFMA GEMM: D(128x128) = A(128xK) * BT(128xK)^T, K=4096, bf16 inputs.
// ---------------------------------------------------------------------------
__device__ __forceinline__ void gemm128x128(
    const bf16_t* __restrict__ A, const bf16_t* __restrict__ BT,
    int ldA, int ldBT, f32x4 acc[4][4])
{
    __shared__ __align__(16) bf16_t As[128 * 32];
    __shared__ __align__(16) bf16_t Bs[128 * 32];

    const int tid  = threadIdx.x;
    const int lane = tid & 63;
    const int wave = tid >> 6;
    const int wr = (wave >> 1) * 64;
    const int wc = (wave & 1) * 64;
    const int srow = tid >> 2;
    const int scol = (tid & 3) * 8;
    const int m0 = wr + (lane & 15);
    const int n0 = wc + (lane & 15);
    const int kq = (lane >> 4) * 8;

    for (int k0 = 0; k0 < NC; k0 += 32) {
        load_lds16(A  + (size_t)srow        * ldA  + k0 + scol, &As[srow * 32 + scol]);
        load_lds16(A  + (size_t)(srow + 64) * ldA  + k0 + scol, &As[(srow + 64) * 32 + scol]);
        load_lds16(BT + (size_t)srow        * ldBT + k0 + scol, &Bs[srow * 32 + scol]);
        load_lds16(BT + (size_t)(srow + 64) * ldBT + k0 + scol, &Bs[(srow + 64) * 32 + scol]);
        __syncthreads();

        bf16x8 af[4], bfr[4];
        #pragma unroll
        for (int i = 0; i < 4; ++i) af[i]  = *(const bf16x8*)&As[(m0 + i * 16) * 32 + kq];
        #pragma unroll
        for (int j = 0; j < 4; ++j) bfr[j] = *(const bf16x8*)&Bs[(n0 + j * 16) * 32 + kq];
        #pragma unroll
        for (int i = 0; i < 4; ++i)
            #pragma unroll
            for (int j = 0; j < 4; ++j)
                acc[i][j] = __builtin_amdgcn_mfma_f32_16x16x32_bf16(af[i], bfr[j], acc[i][j], 0, 0, 0);
        __syncthreads();
    }
}

// ---------------------------------------------------------------------------
// QKV GEMM. q,k written [t][s]; V written TRANSPOSED vT[s][u] for attn phase 3.
// grid.x = B*H = 2048, grid.y = 3.
// ---------------------------------------------------------------------------
__global__ __launch_bounds__(256) void qkv_mfma_kernel(
    const bf16_t* __restrict__ x,
    const bf16_t* __restrict__ wqT, const bf16_t* __restrict__ wkT, const bf16_t* __restrict__ wvT,
    bf16_t* __restrict__ q, bf16_t* __restrict__ k, bf16_t* __restrict__ v)
{
    const int bh = blockIdx.x;
    const int b = bh >> 5, h = bh & 31;
    const bf16_t* wT; bf16_t* o;
    if (blockIdx.y == 0)      { wT = wqT; o = q; }
    else if (blockIdx.y == 1) { wT = wkT; o = k; }
    else                      { wT = wvT; o = v; }

    const bf16_t* A  = x  + (size_t)b * NT * NC;
    const bf16_t* BT = wT + (size_t)h * NHS * NC;
    bf16_t* D = o + (size_t)bh * NT * NHS;

    f32x4 acc[4][4] = {};
    gemm128x128(A, BT, NC, NC, acc);

    const int lane = threadIdx.x & 63;
    const int wave = threadIdx.x >> 6;
    const int wr = (wave >> 1) * 64;
    const int wc = (wave & 1) * 64;
    const int rbase = wr + (lane >> 4) * 4;
    const int col  = wc + (lane & 15);
    if (blockIdx.y == 2) {
        // transposed store: vT[s = col+j*16][u = rbase+i*16+r]
        #pragma unroll
        for (int i = 0; i < 4; ++i)
            #pragma unroll
            for (int j = 0; j < 4; ++j)
                #pragma unroll
                for (int r = 0; r < 4; ++r)
                    D[(size_t)(col + j * 16) * NT + rbase + i * 16 + r] = (bf16_t)acc[i][j][r];
    } else {
        #pragma unroll
        for (int i = 0; i < 4; ++i)
            #pragma unroll
            for (int j = 0; j < 4; ++j)
                #pragma unroll
                for (int r = 0; r < 4; ++r)
                    D[(size_t)(rbase + i * 16 + r) * NHS + col + j * 16] = (bf16_t)acc[i][j][r];
    }
}

// ---------------------------------------------------------------------------
// MFMA attention per (b,h): S = scale*Q*K^T (MFMA) -> column softmax (query
// axis, fp32) -> O^T[s][t] = sum_u vT[s][u] * P[t][u] (MFMA).
// Writes attnT[b][s][h*T+t] bf16. LDS: 8K As + 8K Bs + 34K S = 50 KB.
// ---------------------------------------------------------------------------
__global__ __launch_bounds__(256) void attn_mfma_kernel(
    const bf16_t* __restrict__ q, const bf16_t* __restrict__ k,
    const bf16_t* __restrict__ vT, bf16_t* __restrict__ attnT)
{
    __shared__ __align__(16) bf16_t As[128 * 32];
    __shared__ __align__(16) bf16_t Bs[128 * 32];
    __shared__ __align__(16) bf16_t S[NT * SLD];

    const int bh = blockIdx.x;
    const int b = bh >> 5, h = bh & 31;
    const bf16_t* Q  = q  + (size_t)bh * NT * NHS;
    const bf16_t* K  = k  + (size_t)bh * NT * NHS;
    const bf16_t* VT = vT + (size_t)bh * NT * NHS;

    const int tid  = threadIdx.x;
    const int lane = tid & 63;
    const int wave = tid >> 6;
    const int wr = (wave >> 1) * 64;
    const int wc = (wave & 1) * 64;
    const int srow = tid >> 2;
    const int scol = (tid & 3) * 8;
    const int m0 = wr + (lane & 15);
    const int n0 = wc + (lane & 15);
    const int kq = (lane >> 4) * 8;
    const int rbase = wr + (lane >> 4) * 4;

    f32x4 acc[4][4] = {};

    // Phase 1: S = scale * Q K^T  (contraction over head-dim, 4 steps of 32)
    for (int k0 = 0; k0 < NHS; k0 += 32) {
        load_lds16(Q + (size_t)srow        * NHS + k0 + scol, &As[srow * 32 + scol]);
        load_lds16(Q + (size_t)(srow + 64) * NHS + k0 + scol, &As[(srow + 64) * 32 + scol]);
        load_lds16(K + (size_t)srow        * NHS + k0 + scol, &Bs[srow * 32 + scol]);
        load_lds16(K + (size_t)(srow + 64) * NHS + k0 + scol, &Bs[(srow + 64) * 32 + scol]);
        __syncthreads();
        bf16x8 af[4], bfr[4];
        #pragma unroll
        for (int i = 0; i < 4; ++i) af[i]  = *(const bf16x8*)&As[(m0 + i * 16) * 32 + kq];
        #pragma unroll
        for (int j = 0; j < 4; ++j) bfr[j] = *(const bf16x8*)&Bs[(n0 + j * 16) * 32 + kq];
        #pragma unroll
        for (int i = 0; i < 4; ++i)
            #pragma unroll
            for (int j = 0; j < 4; ++j)
                acc[i][j] = __builtin_amdgcn_mfma_f32_16x16x32_bf16(af[i], bfr[j], acc[i][j], 0, 0, 0);
        __syncthreads();
    }
    // Store S[t][u] = scale * acc (bf16, ld = SLD)
    #pragma unroll
    for (int i = 0; i < 4; ++i)
        #pragma unroll
        for (int j = 0; j < 4; ++j)
            #pragma unroll
            for (int r = 0; r < 4; ++r)
                S[(rbase + i * 16 + r) * SLD + wc + j * 16 + (lane & 15)] =
                    (bf16_t)(acc[i][j][r] * SCALE);
    __syncthreads();

    // Phase 2: softmax over t (query axis) per column u; single fp32 rounding
    if (tid < NT) {
        const int u = tid;
        float m = -1e30f;
        for (int t = 0; t < NT; ++t) m = fmaxf(m, (float)S[t * SLD + u]);
        float sum = 0.f;
        for (int t = 0; t < NT; ++t) sum += __expf((float)S[t * SLD + u] - m);
        const float inv = 1.0f / sum;
        for (int t = 0; t < NT; ++t)
            S[t * SLD + u] = (bf16_t)(__expf((float)S[t * SLD + u] - m) * inv);
    }
    __syncthreads();

    // Phase 3: O^T[s][t] = sum_u VT[s][u] * P[t][u]; A=VT (global), BT=P (LDS)
    #pragma unroll
    for (int i = 0; i < 4; ++i)
        #pragma unroll
        for (int j = 0; j < 4; ++j)
            acc[i][j] = (f32x4)(0.0f);

    for (int k0 = 0; k0 < NT; k0 += 32) {
        load_lds16(VT + (size_t)srow        * NT + k0 + scol, &As[srow * 32 + scol]);
        load_lds16(VT + (size_t)(srow + 64) * NT + k0 + scol, &As[(srow + 64) * 32 + scol]);
        __syncthreads();
        bf16x8 af[4], bfr[4];
        #pragma unroll
        for (int i = 0; i < 4; ++i) af[i]  = *(const bf16x8*)&As[(m0 + i * 16) * 32 + kq];
        #pragma unroll
        for (int j = 0; j < 4; ++j) bfr[j] = *(const bf16x8*)&S[(n0 + j * 16) * SLD + k0 + kq];
        #pragma unroll
        for (int i = 0; i < 4; ++i)
            #pragma unroll
            for (int j = 0; j < 4; ++j)
                acc[i][j] = __builtin_amdgcn_mfma_f32_16x16x32_bf16(af[i], bfr[j], acc[i][j], 0, 0, 0);
        __syncthreads();
    }
    // Epilogue: D[s][t] -> attnT[b][s][h*T + t]
    bf16_t* AT = attnT + (size_t)b * NHS * NC + h * NT;
    #pragma unroll
    for (int i = 0; i < 4; ++i)
        #pragma unroll
        for (int j = 0; j < 4; ++j)
            #pragma unroll
            for (int r = 0; r < 4; ++r)
                AT[(size_t)(rbase + i * 16 + r) * NC + wc + j * 16 + (lane & 15)] =
                    (bf16_t)acc[i][j][r];
}

// ---------------------------------------------------------------------------
// Final projection: out[b][s][o] = attnT[b] (128x4096) * wp_bf^T + bp
// ---------------------------------------------------------------------------
__global__ __launch_bounds__(256) void proj_mfma_kernel(
    const bf16_t* __restrict__ attnT, const bf16_t* __restrict__ wpb,
    const float* __restrict__ bp, float* __restrict__ out)
{
    const int b  = blockIdx.x;
    const int o0 = blockIdx.y * 128;
    const bf16_t* A  = attnT + (size_t)b * NHS * NC;
    const bf16_t* BT = wpb + (size_t)o0 * NC;

    f32x4 acc[4][4] = {};
    gemm128x128(A, BT, NC, NC, acc);

    float* D = out + (size_t)b * NHS * NC + o0;
    const int lane = threadIdx.x & 63;
    const int wave = threadIdx.x >> 6;
    const int wr = (wave >> 1) * 64;
    const int wc = (wave & 1) * 64;
    const int rbase = wr + (lane >> 4) * 4;
    #pragma unroll
    for (int i = 0; i < 4; ++i)
        #pragma unroll
        for (int j = 0; j < 4; ++j) {
            const int n = wc + j * 16 + (lane & 15);
            const float bias = bp[o0 + n];
            #pragma unroll
            for (int r = 0; r < 4; ++r)
                D[(size_t)(rbase + i * 16 + r) * NC + n] = acc[i][j][r] + bias;
        }
}

// ---------------------------------------------------------------------------
extern "C" void kernel_launch(void* const* d_in, const int* in_sizes, int n_in,
                              void* d_out, int out_size, void* d_ws, size_t ws_size,
                              hipStream_t stream) {
    const float* x  = (const float*)d_in[0];
    const float* wq = (const float*)d_in[1];
    const float* wk = (const float*)d_in[2];
    const float* wv = (const float*)d_in[3];
    const float* wp = (const float*)d_in[4];
    const float* bp = (const float*)d_in[5];
    float* out = (float*)d_out;

    const size_t NX = (size_t)NB * NT * NC;     // 33,554,432
    const size_t NW = (size_t)NH * NC * NHS;    // 16,777,216
    bf16_t* xb  = (bf16_t*)d_ws;
    bf16_t* wqT = xb  + NX;
    bf16_t* wkT = wqT + NW;
    bf16_t* wvT = wkT + NW;
    bf16_t* wpb = wvT + NW;
    bf16_t* qb  = wpb + NW;
    bf16_t* kb  = qb  + NX;
    bf16_t* vb  = kb  + NX;   // holds vT [bh][s][u]
    bf16_t* atT = vb  + NX;

    cvt_bf16_kernel<<<(int)(NX / 8 / 256), 256, 0, stream>>>(x, xb, (int)(NX / 8));
    cvt_w_transpose_kernel<<<dim3(4096, 3), 256, 0, stream>>>(wq, wk, wv, wqT, wkT, wvT);
    cvt_bf16_kernel<<<(int)(NW / 8 / 256), 256, 0, stream>>>(wp, wpb, (int)(NW / 8));

    qkv_mfma_kernel<<<dim3(NB * NH, 3), 256, 0, stream>>>(xb, wqT, wkT, wvT, qb, kb, vb);
    attn_mfma_kernel<<<NB * NH, 256, 0, stream>>>(qb, kb, vb, atT);
    proj_mfma_kernel<<<dim3(NB, 32), 256, 0, stream>>>(atT, wpb, bp, out);
}